// Round 7
// baseline (739.483 us; speedup 1.0000x reference)
//
#include <hip/hip_runtime.h>
#include <stdint.h>

// Capsule routing, f32 in/out. B=32, Nin=2048, Din=16, Nout=64, Dout=32, 3 iters.
// Round 7: pass0 fuses the f16-W transcode into its mandatory f32-W sweep;
// IT passes use G=16 batch blocking (halves W L3 traffic) at 1 block/CU
// (launch_bounds(512,1) => 256-VGPR budget) with explicit double-buffered
// W-fragment prefetch; phase-split (logits -> softmax -> accumulate) retained.

#define CB    32
#define NIN   2048
#define DIN   16
#define NOUT  64
#define DOUT  32
#define CHUNK 16
#define NCHUNK (NIN / CHUNK)     // 128
#define WI    (NOUT * DOUT * DIN)          // 32768 elements per i
#define WELEM ((size_t)NIN * WI)           // 67,108,864

typedef _Float16 h2 __attribute__((ext_vector_type(2)));

static __device__ __forceinline__ h2 as_h2(uint32_t u) {
    h2 r; __builtin_memcpy(&r, &u, 4); return r;
}
static __device__ __forceinline__ uint32_t pack_h2(float a, float b) {
    h2 r; r.x = (_Float16)a; r.y = (_Float16)b;
    uint32_t u; __builtin_memcpy(&u, &r, 4); return u;
}

// uh[4] = 4 W-rows (f16 pairs in wq[8]) dot x (16 k, h2 pairs in xA/xB)
static __device__ __forceinline__ void uh_f16(const uint4* wq, uint4 xA, uint4 xB, float* uh) {
#pragma unroll
    for (int r = 0; r < 4; ++r) {
        float a = 0.f;
        a = __builtin_amdgcn_fdot2(as_h2(wq[2*r].x),   as_h2(xA.x), a, false);
        a = __builtin_amdgcn_fdot2(as_h2(wq[2*r].y),   as_h2(xA.y), a, false);
        a = __builtin_amdgcn_fdot2(as_h2(wq[2*r].z),   as_h2(xA.z), a, false);
        a = __builtin_amdgcn_fdot2(as_h2(wq[2*r].w),   as_h2(xA.w), a, false);
        a = __builtin_amdgcn_fdot2(as_h2(wq[2*r+1].x), as_h2(xB.x), a, false);
        a = __builtin_amdgcn_fdot2(as_h2(wq[2*r+1].y), as_h2(xB.y), a, false);
        a = __builtin_amdgcn_fdot2(as_h2(wq[2*r+1].z), as_h2(xB.z), a, false);
        a = __builtin_amdgcn_fdot2(as_h2(wq[2*r+1].w), as_h2(xB.w), a, false);
        uh[r] = a;
    }
}

// ---------------- Pass 0: uniform coupling; streams f32 W, emits f16 W ----------------
// grid 512 (128 chunks x 4 bg), G=8, 1 block/CU => 256-VGPR budget, full prefetch.
__global__ __launch_bounds__(512, 1) void caps_pass0(
    const float* __restrict__ x, const float* __restrict__ W,
    uint32_t* __restrict__ Wh, float* __restrict__ s_partial)
{
    const int p     = blockIdx.x;
    const int chunk = (p >> 5) * 8 + (p & 7);     // 4 bg of a chunk share an XCD
    const int bg    = (p & 31) >> 3;
    const int b0    = bg * 8;
    const int t     = threadIdx.x;
    const int j     = t >> 3, dq = t & 7;

    __shared__ float sh_x[8 * CHUNK * DIN];       // 8KB
    {
        const int bb = t >> 6, rem = t & 63;
        *(float4*)&sh_x[bb * (CHUNK * DIN) + rem * 4] =
            *(const float4*)(x + (size_t)(b0 + bb) * (NIN * DIN)
                               + (size_t)chunk * (CHUNK * DIN) + rem * 4);
    }
    __syncthreads();

    float sacc[8][4];
#pragma unroll
    for (int bb = 0; bb < 8; ++bb)
#pragma unroll
        for (int r = 0; r < 4; ++r) sacc[bb][r] = 0.f;

    const size_t thrW = (size_t)j * (DOUT * DIN) + (size_t)(dq * 4) * DIN;

    auto LD = [&](float4* dst, int ii) {
        const float4* wp = (const float4*)(W + (size_t)(chunk * CHUNK + ii) * WI + thrW);
#pragma unroll
        for (int q = 0; q < 16; ++q) dst[q] = wp[q];
    };
    auto BODY = [&](const float4* wf, int ii) {
        const int i = chunk * CHUNK + ii;
        if (Wh != nullptr && bg == (ii & 3)) {     // each i emitted by exactly one bg
            uint32_t* dst = Wh + ((size_t)i * WI + thrW) / 2;
#pragma unroll
            for (int g8 = 0; g8 < 8; ++g8) {
                uint4 pk;
                pk.x = pack_h2(wf[2*g8].x,   wf[2*g8].y);
                pk.y = pack_h2(wf[2*g8].z,   wf[2*g8].w);
                pk.z = pack_h2(wf[2*g8+1].x, wf[2*g8+1].y);
                pk.w = pack_h2(wf[2*g8+1].z, wf[2*g8+1].w);
                *(uint4*)(dst + g8 * 4) = pk;
            }
        }
#pragma unroll
        for (int bb = 0; bb < 8; ++bb) {
            const float4* xp = (const float4*)&sh_x[bb * (CHUNK * DIN) + ii * DIN];
            const float4 x0 = xp[0], x1 = xp[1], x2 = xp[2], x3 = xp[3];
#pragma unroll
            for (int r = 0; r < 4; ++r) {
                const float4 wA = wf[r*4+0], wB = wf[r*4+1], wC = wf[r*4+2], wD = wf[r*4+3];
                sacc[bb][r] += wA.x*x0.x + wA.y*x0.y + wA.z*x0.z + wA.w*x0.w
                             + wB.x*x1.x + wB.y*x1.y + wB.z*x1.z + wB.w*x1.w
                             + wC.x*x2.x + wC.y*x2.y + wC.z*x2.z + wC.w*x2.w
                             + wD.x*x3.x + wD.y*x3.y + wD.z*x3.z + wD.w*x3.w;
            }
        }
    };

    float4 wfA[16], wfB[16];
    LD(wfA, 0);
#pragma unroll 1
    for (int ii = 0; ii < CHUNK; ii += 2) {
        LD(wfB, ii + 1);
        BODY(wfA, ii);
        if (ii + 2 < CHUNK) LD(wfA, ii + 2);
        BODY(wfB, ii + 1);
    }

#pragma unroll
    for (int bb = 0; bb < 8; ++bb) {
        float4 o;
        o.x = sacc[bb][0] * (1.0f/64.0f); o.y = sacc[bb][1] * (1.0f/64.0f);
        o.z = sacc[bb][2] * (1.0f/64.0f); o.w = sacc[bb][3] * (1.0f/64.0f);
        *(float4*)(s_partial + ((size_t)(b0 + bb) * NCHUNK + chunk) * (NOUT * DOUT) + t * 4) = o;
    }
}

// ---------------- IT passes: G=16, phase-split, prefetched f16 W ----------------
// grid 256 (128 chunks x 2 bg), 1 block/CU. Dynamic LDS: sh_c 64KB + sh_xh 8KB.
#define ITSMEM (16 * CHUNK * NOUT * 4 + 16 * CHUNK * 8 * 4)   // 73728

template <int IT, bool F16>
__global__ __launch_bounds__(512, 1) void caps_passit(
    const float* __restrict__ x, const void* __restrict__ Wv,
    const float* __restrict__ v_prev, const float* __restrict__ blog_in,
    float* __restrict__ blog_out, float* __restrict__ s_partial)
{
    extern __shared__ char smem[];
    float*    sh_c  = (float*)smem;                       // [16*CHUNK][NOUT]
    uint32_t* sh_xh = (uint32_t*)(smem + 16 * CHUNK * NOUT * 4);  // [16*CHUNK][8]

    const int p     = blockIdx.x;                 // 256
    const int chunk = (p >> 4) * 8 + (p & 7);     // 2 bg of a chunk share an XCD
    const int bg    = (p >> 3) & 1;
    const int b0    = bg * 16;
    const int t     = threadIdx.x;
    const int j     = t >> 3, dq = t & 7;
    const int w     = t >> 6, l = t & 63;

    // stage x as packed h2: 16 b x 16 i x 16 k = 1024 float4, 2 per thread
#pragma unroll
    for (int rep = 0; rep < 2; ++rep) {
        const int f4 = t + rep * 512;
        const int bb = f4 >> 6, rem = f4 & 63;
        const float4 xv = *(const float4*)(x + (size_t)(b0 + bb) * (NIN * DIN)
                                             + (size_t)chunk * (CHUNK * DIN) + rem * 4);
        sh_xh[f4 * 2 + 0] = pack_h2(xv.x, xv.y);
        sh_xh[f4 * 2 + 1] = pack_h2(xv.z, xv.w);
    }

    // v for this thread's (j, d-quad), packed h2: 2 dwords per b
    uint2 vrp[16];
#pragma unroll
    for (int bb = 0; bb < 16; ++bb) {
        const float4 v4 = *(const float4*)(v_prev + (size_t)(b0 + bb) * (NOUT * DOUT)
                                           + j * DOUT + dq * 4);
        vrp[bb].x = pack_h2(v4.x, v4.y);
        vrp[bb].y = pack_h2(v4.z, v4.w);
    }
    __syncthreads();

    const size_t thrW = (size_t)j * (DOUT * DIN) + (size_t)(dq * 4) * DIN;
    const uint32_t* Wb = (const uint32_t*)Wv;

    auto LDW = [&](uint4* dst, int ii) {
        if constexpr (F16) {
            const uint4* wp = (const uint4*)(Wb + ((size_t)(chunk * CHUNK + ii) * WI + thrW) / 2);
#pragma unroll
            for (int q = 0; q < 8; ++q) dst[q] = wp[q];
        } else {
            const float4* wp = (const float4*)((const float*)Wv
                               + (size_t)(chunk * CHUNK + ii) * WI + thrW);
#pragma unroll
            for (int q = 0; q < 8; ++q) {
                const float4 a = wp[2*q], b = wp[2*q+1];
                dst[q].x = pack_h2(a.x, a.y); dst[q].y = pack_h2(a.z, a.w);
                dst[q].z = pack_h2(b.x, b.y); dst[q].w = pack_h2(b.z, b.w);
            }
        }
    };

    // ================= PHASE A: logits for all i (no barriers) =================
    auto LOGITS = [&](const uint4* wq, int ii) {
#pragma unroll
        for (int bb = 0; bb < 16; ++bb) {
            const uint4 xA = *(const uint4*)&sh_xh[(bb * CHUNK + ii) * 8];
            const uint4 xB = *(const uint4*)&sh_xh[(bb * CHUNK + ii) * 8 + 4];
            float uh[4]; uh_f16(wq, xA, xB, uh);
            float dlg = __builtin_amdgcn_fdot2(as_h2(pack_h2(uh[0], uh[1])),
                                               as_h2(vrp[bb].x), 0.f, false);
            dlg = __builtin_amdgcn_fdot2(as_h2(pack_h2(uh[2], uh[3])),
                                         as_h2(vrp[bb].y), dlg, false);
            dlg += __shfl_xor(dlg, 1);
            dlg += __shfl_xor(dlg, 2);
            dlg += __shfl_xor(dlg, 4);
            if (dq == 0) sh_c[(bb * CHUNK + ii) * NOUT + j] = dlg;
        }
    };

    {
        uint4 wA[8], wB[8];
        LDW(wA, 0);
#pragma unroll 1
        for (int ii = 0; ii < CHUNK; ii += 2) {
            LDW(wB, ii + 1);
            LOGITS(wA, ii);
            if (ii + 2 < CHUNK) LDW(wA, ii + 2);
            LOGITS(wB, ii + 1);
        }
    }
    __syncthreads();

    // ================= PHASE B: softmax (wave w owns batches w, w+8) =================
#pragma unroll
    for (int bh = 0; bh < 2; ++bh) {
        const int bb = w + bh * 8;
        const int b  = b0 + bb;
        for (int q = 0; q < CHUNK; ++q) {
            const int i = chunk * CHUNK + q;
            float bl = sh_c[(bb * CHUNK + q) * NOUT + l];
            if constexpr (IT == 2) bl += blog_in[((size_t)b * NIN + i) * NOUT + l];
            if constexpr (IT == 1) blog_out[((size_t)b * NIN + i) * NOUT + l] = bl;
            float m = bl;
#pragma unroll
            for (int o = 32; o; o >>= 1) m = fmaxf(m, __shfl_xor(m, o));
            const float e = __expf(bl - m);
            float s = e;
#pragma unroll
            for (int o = 32; o; o >>= 1) s += __shfl_xor(s, o);
            sh_c[(bb * CHUNK + q) * NOUT + l] = e / s;
        }
    }
    __syncthreads();

    // ================= PHASE C: recompute u_hat, accumulate c*u_hat =================
    float sacc[16][4];
#pragma unroll
    for (int bb = 0; bb < 16; ++bb)
#pragma unroll
        for (int r = 0; r < 4; ++r) sacc[bb][r] = 0.f;

    auto ACC = [&](const uint4* wq, int ii) {
#pragma unroll
        for (int bb = 0; bb < 16; ++bb) {
            const uint4 xA = *(const uint4*)&sh_xh[(bb * CHUNK + ii) * 8];
            const uint4 xB = *(const uint4*)&sh_xh[(bb * CHUNK + ii) * 8 + 4];
            float uh[4]; uh_f16(wq, xA, xB, uh);
            const float c = sh_c[(bb * CHUNK + ii) * NOUT + j];
#pragma unroll
            for (int r = 0; r < 4; ++r) sacc[bb][r] += c * uh[r];
        }
    };

    {
        uint4 wA[8], wB[8];
        LDW(wA, 0);
#pragma unroll 1
        for (int ii = 0; ii < CHUNK; ii += 2) {
            LDW(wB, ii + 1);
            ACC(wA, ii);
            if (ii + 2 < CHUNK) LDW(wA, ii + 2);
            ACC(wB, ii + 1);
        }
    }

#pragma unroll
    for (int bb = 0; bb < 16; ++bb) {
        float4 o;
        o.x = sacc[bb][0]; o.y = sacc[bb][1]; o.z = sacc[bb][2]; o.w = sacc[bb][3];
        *(float4*)(s_partial + ((size_t)(b0 + bb) * NCHUNK + chunk) * (NOUT * DOUT) + t * 4) = o;
    }
}

// ---------------- Reduce partials, add bias, squash. One wave per (b,j). ----------------
__global__ __launch_bounds__(64) void caps_squash(
    const float* __restrict__ s_partial,  // [B, NCHUNK, NOUT*DOUT]
    const float* __restrict__ bias,       // [NOUT, DOUT]
    float* __restrict__ v_out)            // [B, NOUT, DOUT]
{
    const int bj = blockIdx.x;
    const int b  = bj / NOUT;
    const int j  = bj % NOUT;
    const int t  = threadIdx.x;
    const int d  = t & 31;
    const int h  = t >> 5;

    float sv = 0.f;
    for (int c = h; c < NCHUNK; c += 2)
        sv += s_partial[((size_t)b * NCHUNK + c) * (NOUT * DOUT) + j * DOUT + d];
    sv += __shfl_xor(sv, 32);
    sv += bias[j * DOUT + d];

    float sq = sv * sv;
#pragma unroll
    for (int o = 16; o; o >>= 1) sq += __shfl_xor(sq, o);

    float scale = (sq / (1.0f + sq)) * rsqrtf(sq + 1e-9f);
    float v = scale * sv;
    if (t < 32) v_out[((size_t)b * NOUT + j) * DOUT + d] = v;
}

extern "C" void kernel_launch(void* const* d_in, const int* in_sizes, int n_in,
                              void* d_out, int out_size, void* d_ws, size_t ws_size,
                              hipStream_t stream) {
    const float* x    = (const float*)d_in[0];
    const float* W    = (const float*)d_in[1];
    const float* bias = (const float*)d_in[2];
    float* out = (float*)d_out;

    const size_t nblog  = (size_t)CB * NIN * NOUT;           // 4,194,304 f (16MB)
    const size_t nspart = (size_t)CB * NCHUNK * NOUT * DOUT; // 8,388,608 f (33.5MB)
    const size_t nv     = (size_t)CB * NOUT * DOUT;          // 65,536 f
    const size_t wh_bytes   = WELEM * 2;                     // 134MB (f16 W)
    const size_t rest_bytes = (nblog + nspart + nv) * 4;
    const bool useH = ws_size >= wh_bytes + rest_bytes;

    char* base = (char*)d_ws;
    uint32_t* Wh = useH ? (uint32_t*)base : nullptr;
    float* blog  = (float*)(base + (useH ? wh_bytes : 0));
    float* spart = blog + nblog;
    float* vbuf  = spart + nspart;

    // raise dynamic LDS limit for the IT kernels (host-side, graph-safe)
    hipFuncSetAttribute(reinterpret_cast<const void*>(caps_passit<1, true>),
                        hipFuncAttributeMaxDynamicSharedMemorySize, ITSMEM);
    hipFuncSetAttribute(reinterpret_cast<const void*>(caps_passit<2, true>),
                        hipFuncAttributeMaxDynamicSharedMemorySize, ITSMEM);
    hipFuncSetAttribute(reinterpret_cast<const void*>(caps_passit<1, false>),
                        hipFuncAttributeMaxDynamicSharedMemorySize, ITSMEM);
    hipFuncSetAttribute(reinterpret_cast<const void*>(caps_passit<2, false>),
                        hipFuncAttributeMaxDynamicSharedMemorySize, ITSMEM);

    caps_pass0<<<512, 512, 0, stream>>>(x, W, Wh, spart);
    caps_squash<<<CB * NOUT, 64, 0, stream>>>(spart, bias, vbuf);

    if (useH) {
        caps_passit<1, true><<<256, 512, ITSMEM, stream>>>(x, Wh, vbuf, nullptr, blog, spart);
        caps_squash<<<CB * NOUT, 64, 0, stream>>>(spart, bias, vbuf);
        caps_passit<2, true><<<256, 512, ITSMEM, stream>>>(x, Wh, vbuf, blog, nullptr, spart);
    } else {
        caps_passit<1, false><<<256, 512, ITSMEM, stream>>>(x, W, vbuf, nullptr, blog, spart);
        caps_squash<<<CB * NOUT, 64, 0, stream>>>(spart, bias, vbuf);
        caps_passit<2, false><<<256, 512, ITSMEM, stream>>>(x, W, vbuf, blog, nullptr, spart);
    }
    caps_squash<<<CB * NOUT, 64, 0, stream>>>(spart, bias, out);
}

// Round 8
// 594.850 us; speedup vs baseline: 1.2431x; 1.2431x over previous
//
#include <hip/hip_runtime.h>
#include <hip/hip_bf16.h>
#include <stdint.h>

// Capsule routing, f32 in/out. B=32, Nin=2048, Din=16, Nout=64, Dout=32, 3 iters.
// Round 8: MFMA formulation. Per i: D[jd,b] = W_i[16x32k] * x_i^T[32k x 16b]
// via mfma_f32_16x16x32_bf16 with K zero-padded (lanes 32-63 = zero frags).
// One block = (16-i chunk, 16-batch group); phases: A logits(all i) -> B softmax
// -> C weighted accumulate; sacc and v-regs live in disjoint phases (<=~110 VGPR).

#define CB    32
#define NIN   2048
#define DIN   16
#define NOUT  64
#define DOUT  32
#define IPB   16                     // i's per block
#define NCB   (NIN / IPB)            // 128 chunk-blocks
#define WI    (NOUT * DOUT * DIN)    // 32768 elements per i
#define WELEM ((size_t)NIN * WI)     // 67,108,864

typedef __attribute__((ext_vector_type(8))) short bf16x8;
typedef __attribute__((ext_vector_type(4))) float f32x4;

static __device__ __forceinline__ uint32_t pack_bf2(float a, float b) {
    __hip_bfloat162 h = __float22bfloat162_rn(make_float2(a, b));
    uint32_t u; __builtin_memcpy(&u, &h, 4); return u;
}

// ---------------- W f32 -> bf16 transcode (pure streaming) ----------------
__global__ __launch_bounds__(256) void transcode(
    const float* __restrict__ W, uint32_t* __restrict__ Wb)
{
    const size_t stride = (size_t)gridDim.x * 256;
    for (size_t q = (size_t)blockIdx.x * 256 + threadIdx.x; q < WELEM / 8; q += stride) {
        const float4 a = *(const float4*)(W + q * 8);
        const float4 b = *(const float4*)(W + q * 8 + 4);
        uint4 o;
        o.x = pack_bf2(a.x, a.y); o.y = pack_bf2(a.z, a.w);
        o.z = pack_bf2(b.x, b.y); o.w = pack_bf2(b.z, b.w);
        *(uint4*)(Wb + q * 4) = o;
    }
}

// ---------------- MFMA routing pass ----------------
// grid 256: p -> chunk cb = (p>>4)*8 + (p&7) (both bg of a chunk on one XCD),
// bg = (p>>3)&1, b0 = bg*16. 512 threads = 8 waves; wave w owns j in [w*8, w*8+8).
// Dynamic LDS: IT>0: c[16][64][17] f32 (69632) + x[16][16][16] bf16 (8192); t aliases c.
//              IT=0: t (34816) + x (8192).
template <int IT>
__global__ __launch_bounds__(512, 2) void caps_mfma(
    const float* __restrict__ x, const uint16_t* __restrict__ Wh,
    const float* __restrict__ v_prev, const float* __restrict__ blog_in,
    float* __restrict__ blog_out, float* __restrict__ s_partial)
{
    extern __shared__ char smem[];
    constexpr size_t C_OFF = 0;
    constexpr size_t X_OFF = (IT > 0) ? 69632 : 34816;
    float*    c_lds = (float*)(smem + C_OFF);      // [16][64][17] (IT>0)
    uint16_t* x_lds = (uint16_t*)(smem + X_OFF);   // [16][16][16] bf16
    float*    t_lds = (float*)smem;                // [512][17] transpose (aliases c)

    const int p  = blockIdx.x;
    const int cb = (p >> 4) * 8 + (p & 7);
    const int bg = (p >> 3) & 1;
    const int b0 = bg * 16;
    const int t  = threadIdx.x;
    const int w  = t >> 6, l = t & 63;
    const bool lo32 = (l < 32);
    const int lb = l & 15;          // b (N) / jd-low (M) index
    const int lg = l >> 4;          // k-group / row-group

    // ---- stage x -> bf16 LDS [i][b][k] ----
    for (int q = t; q < IPB * 16 * 16 / 4; q += 512) {     // 1024 quads
        const int i = q >> 6, b = (q >> 2) & 15, k4 = (q & 3) * 4;
        const float4 xv = *(const float4*)(x + ((size_t)(b0 + b) * NIN + cb * IPB + i) * DIN + k4);
        uint2 uu;
        uu.x = pack_bf2(xv.x, xv.y);
        uu.y = pack_bf2(xv.z, xv.w);
        *(uint2*)&x_lds[(i * 16 + b) * 16 + k4] = uu;
    }
    __syncthreads();

    const f32x4  zacc  = {0.f, 0.f, 0.f, 0.f};
    const bf16x8 zfrag = {0, 0, 0, 0, 0, 0, 0, 0};

    if (IT > 0) {
        // v for this lane: v[b=lb][j = w*8+jj][d = lg*4 + r (+16)], f32
        float4 vlo[8], vhi[8];
#pragma unroll
        for (int jj = 0; jj < 8; ++jj) {
            const float* vp = v_prev + ((size_t)(b0 + lb) * NOUT + (w * 8 + jj)) * DOUT + lg * 4;
            vlo[jj] = *(const float4*)vp;
            vhi[jj] = *(const float4*)(vp + 16);
        }

        // ============ PHASE A: logits for all 16 i (no barriers) ============
#pragma unroll 1
        for (int ii = 0; ii < IPB; ++ii) {
            const int ig = cb * IPB + ii;
            bf16x8 bfr = zfrag;
            if (lo32) bfr = *(const bf16x8*)&x_lds[(ii * 16 + lb) * 16 + lg * 8];
            const uint16_t* wbase = Wh + (size_t)ig * WI;
#pragma unroll
            for (int jj = 0; jj < 8; ++jj) {
                const int jd0 = (w * 8 + jj) * 32;
                bf16x8 a0 = zfrag, a1 = zfrag;
                if (lo32) {
                    a0 = *(const bf16x8*)(wbase + (size_t)(jd0 + lb) * 16 + lg * 8);
                    a1 = *(const bf16x8*)(wbase + (size_t)(jd0 + 16 + lb) * 16 + lg * 8);
                }
                f32x4 d0 = __builtin_amdgcn_mfma_f32_16x16x32_bf16(a0, bfr, zacc, 0, 0, 0);
                f32x4 d1 = __builtin_amdgcn_mfma_f32_16x16x32_bf16(a1, bfr, zacc, 0, 0, 0);
                float pl = d0[0]*vlo[jj].x + d0[1]*vlo[jj].y + d0[2]*vlo[jj].z + d0[3]*vlo[jj].w
                         + d1[0]*vhi[jj].x + d1[1]*vhi[jj].y + d1[2]*vhi[jj].z + d1[3]*vhi[jj].w;
                pl += __shfl_xor(pl, 16);
                pl += __shfl_xor(pl, 32);
                if (l < 16) c_lds[(ii * 64 + w * 8 + jj) * 17 + l] = pl;
            }
        }
        __syncthreads();

        // ============ PHASE B: softmax over j, 256 rows (i,b) ============
#pragma unroll 1
        for (int q = 0; q < 32; ++q) {
            const int row = w * 32 + q;
            const int ii = row >> 4, b = row & 15;
            const int ig = cb * IPB + ii;
            float bl = c_lds[(ii * 64 + l) * 17 + b];
            if (IT == 2) bl += blog_in[((size_t)(b0 + b) * NIN + ig) * NOUT + l];
            if (IT == 1) blog_out[((size_t)(b0 + b) * NIN + ig) * NOUT + l] = bl;
            float m = bl;
#pragma unroll
            for (int o = 32; o; o >>= 1) m = fmaxf(m, __shfl_xor(m, o));
            const float e = __expf(bl - m);
            float s = e;
#pragma unroll
            for (int o = 32; o; o >>= 1) s += __shfl_xor(s, o);
            c_lds[(ii * 64 + l) * 17 + b] = e / s;
        }
        __syncthreads();
    }

    // ============ PHASE C: accumulate c * u_hat ============
    f32x4 sacc[16];
#pragma unroll
    for (int m = 0; m < 16; ++m) sacc[m] = zacc;

#pragma unroll 1
    for (int ii = 0; ii < IPB; ++ii) {
        const int ig = cb * IPB + ii;
        bf16x8 bfr = zfrag;
        if (lo32) bfr = *(const bf16x8*)&x_lds[(ii * 16 + lb) * 16 + lg * 8];
        const uint16_t* wbase = Wh + (size_t)ig * WI;
#pragma unroll
        for (int m = 0; m < 16; ++m) {
            const int jd0 = (w * 8 + (m >> 1)) * 32 + (m & 1) * 16;
            bf16x8 a0 = zfrag;
            if (lo32) a0 = *(const bf16x8*)(wbase + (size_t)(jd0 + lb) * 16 + lg * 8);
            f32x4 d = __builtin_amdgcn_mfma_f32_16x16x32_bf16(a0, bfr, zacc, 0, 0, 0);
            const float cv = (IT == 0) ? (1.0f / 64.0f)
                                       : c_lds[(ii * 64 + w * 8 + (m >> 1)) * 17 + lb];
#pragma unroll
            for (int r = 0; r < 4; ++r) sacc[m][r] += cv * d[r];
        }
    }
    __syncthreads();   // c_lds dead; t_lds (alias) safe to write

    // ============ transpose-store via LDS: spart[cb][b][jd], coalesced ============
#pragma unroll 1
    for (int part = 0; part < 4; ++part) {
        if ((w >> 1) == part) {
            const int wl = w & 1;
#pragma unroll
            for (int m = 0; m < 16; ++m) {
                const int jdl = wl * 256 + (m >> 1) * 32 + (m & 1) * 16 + lg * 4;
#pragma unroll
                for (int r = 0; r < 4; ++r)
                    t_lds[(jdl + r) * 17 + lb] = sacc[m][r];
            }
        }
        __syncthreads();
        {
            const int b = t >> 5, j0 = t & 31;
            float* dst = s_partial + ((size_t)cb * CB + b0 + b) * 2048 + part * 512;
#pragma unroll
            for (int q = 0; q < 16; ++q)
                dst[j0 + q * 32] = t_lds[(j0 + q * 32) * 17 + b];
        }
        __syncthreads();
    }
}

// ---------------- Reduce partials over chunk-blocks, add bias, squash ----------------
// s_partial layout: [cb 128][b 32][jd 2048]. One wave per (b,j).
__global__ __launch_bounds__(64) void caps_squash(
    const float* __restrict__ s_partial,
    const float* __restrict__ bias,       // [NOUT, DOUT]
    float* __restrict__ v_out)            // [B, NOUT, DOUT]
{
    const int bj = blockIdx.x;
    const int b  = bj / NOUT;
    const int j  = bj % NOUT;
    const int t  = threadIdx.x;
    const int d  = t & 31;
    const int h  = t >> 5;

    float sv = 0.f;
    for (int c = h; c < NCB; c += 2)
        sv += s_partial[((size_t)c * CB + b) * 2048 + j * DOUT + d];
    sv += __shfl_xor(sv, 32);
    sv += bias[j * DOUT + d];

    float sq = sv * sv;
#pragma unroll
    for (int o = 16; o; o >>= 1) sq += __shfl_xor(sq, o);

    float scale = (sq / (1.0f + sq)) * rsqrtf(sq + 1e-9f);
    float v = scale * sv;
    if (t < 32) v_out[((size_t)b * NOUT + j) * DOUT + d] = v;
}

extern "C" void kernel_launch(void* const* d_in, const int* in_sizes, int n_in,
                              void* d_out, int out_size, void* d_ws, size_t ws_size,
                              hipStream_t stream) {
    const float* x    = (const float*)d_in[0];
    const float* W    = (const float*)d_in[1];
    const float* bias = (const float*)d_in[2];
    float* out = (float*)d_out;

    const size_t wh_bytes = WELEM * 2;                       // 134,217,728
    const size_t nblog    = (size_t)CB * NIN * NOUT;         // 4,194,304 f
    const size_t nspart   = (size_t)NCB * CB * 2048;         // 8,388,608 f
    char* base = (char*)d_ws;
    uint16_t* Wh = (uint16_t*)base;
    float* blog  = (float*)(base + wh_bytes);
    float* spart = blog + nblog;
    float* vbuf  = spart + nspart;
    (void)ws_size;  // requires ~185MB; harness has provided >= this in all prior rounds

    const int SM0 = 34816 + 8192;   // IT=0: t_lds + x_lds
    const int SM1 = 69632 + 8192;   // IT>0: c_lds (t aliases) + x_lds

    hipFuncSetAttribute(reinterpret_cast<const void*>(caps_mfma<0>),
                        hipFuncAttributeMaxDynamicSharedMemorySize, SM0);
    hipFuncSetAttribute(reinterpret_cast<const void*>(caps_mfma<1>),
                        hipFuncAttributeMaxDynamicSharedMemorySize, SM1);
    hipFuncSetAttribute(reinterpret_cast<const void*>(caps_mfma<2>),
                        hipFuncAttributeMaxDynamicSharedMemorySize, SM1);

    transcode<<<2048, 256, 0, stream>>>(W, (uint32_t*)Wh);

    caps_mfma<0><<<256, 512, SM0, stream>>>(x, Wh, nullptr, nullptr, nullptr, spart);
    caps_squash<<<CB * NOUT, 64, 0, stream>>>(spart, bias, vbuf);

    caps_mfma<1><<<256, 512, SM1, stream>>>(x, Wh, vbuf, nullptr, blog, spart);
    caps_squash<<<CB * NOUT, 64, 0, stream>>>(spart, bias, vbuf);

    caps_mfma<2><<<256, 512, SM1, stream>>>(x, Wh, vbuf, blog, nullptr, spart);
    caps_squash<<<CB * NOUT, 64, 0, stream>>>(spart, bias, out);
}